// Round 10
// baseline (80.317 us; speedup 1.0000x reference)
//
#include <hip/hip_runtime.h>

// ---------------------------------------------------------------------------
// TreeEncoder fused MFMA kernel, round 10.
//   r8 (59.4us) vs r9 (61us) proved the fragment stream's PIPE is irrelevant:
//   the cost is that every wave privately consumes the same 12KB/step
//   broadcast (per CU: 16 waves x 12KB ~= 3000cy/step on L2 *or* LDS).
//   Per-SIMD VALU/MFMA totals are rows-per-wave-invariant, so the only term
//   that shrinks with bigger row tiles is this broadcast traffic.
//   Round 10: 64 rows/wave (halves broadcast), UNCAPPED VGPR (~180; the r2/r3
//   64-row attempts died purely from the 128-cap spilling 105-148MB),
//   zero inner barriers, single-buffer WAR fragment reload (r8 discipline).
//   + bias-splat accumulator init (kills 3 adds/elem; movs were spent anyway)
//   + single-rcp rational activation: h = p*N / (q*D*(1+eo)), Pade in
//     homogeneous (p,q) form: 4 trans + ~19 VALU per element (was 5 + ~22).
//   Grid 512 x 256: 2 blocks/CU, 8 waves/CU (2/SIMD) -- the bet is that
//   doubled in-wave MLP (48 MFMAs per 12-load set, 16-elem act chains)
//   compensates the halved wave count.
// ---------------------------------------------------------------------------

typedef short bf16x8 __attribute__((ext_vector_type(8)));
typedef float f32x4  __attribute__((ext_vector_type(4)));

#define MFMA16(a, b, c) __builtin_amdgcn_mfma_f32_16x16x32_bf16((a), (b), (c), 0, 0, 0)

#define NEG_L2E (-1.44269504088896f)
#define TWO_L2E (2.88539008177793f)

__device__ __forceinline__ unsigned short f2bf(float f) {
    return (unsigned short)((__float_as_uint(f) + 0x8000u) >> 16);
}
__device__ __forceinline__ float frcp(float x)  { return __builtin_amdgcn_rcpf(x); }
__device__ __forceinline__ float fexp2(float x) { return __builtin_amdgcn_exp2f(x); }

// ---------------------------------------------------------------------------
// Prep: weights -> MFMA B-fragment bf16 layout in ws, with exp2 prescale;
// plus combined scaled biases.  (identical to rounds 8/9)
//   ws map (bytes):
//     [0, 16384)        emb_W: block = t*2 + kk          (unscaled)
//     [16384, 212992)   gates: block = (layer*8+t)*12 + gate*4 + kk
//         gate 0/1 (Wi,Wo): * -log2e    gate 2 (Wc): * 2*log2e
//     [212992, 216064)  biases: float[2][3][128], same scaling, bW+bU combined
// ---------------------------------------------------------------------------
__global__ void prep_frags(const float* __restrict__ embW,
                           const float* __restrict__ Wi,
                           const float* __restrict__ Wo,
                           const float* __restrict__ Wc,
                           const float* __restrict__ bWi, const float* __restrict__ bUi,
                           const float* __restrict__ bWo, const float* __restrict__ bUo,
                           const float* __restrict__ bWc, const float* __restrict__ bUc,
                           char* __restrict__ ws) {
    int fb = blockIdx.x;          // 0..208
    int l  = threadIdx.x;         // 0..63

    if (fb == 208) {              // combined scaled biases: [layer][gate][128]
        float* bias = reinterpret_cast<float*>(ws + 212992);
#pragma unroll
        for (int j = 0; j < 12; ++j) {
            int v = j * 64 + l;                 // 0..767
            int layer = v / 384;
            int r = v % 384;
            int gate = r >> 7;
            int c = r & 127;
            int idx = layer * 128 + c;
            float x;
            if (gate == 0)      x = NEG_L2E * (bWi[idx] + bUi[idx]);
            else if (gate == 1) x = NEG_L2E * (bWo[idx] + bUo[idx]);
            else                x = TWO_L2E * (bWc[idx] + bUc[idx]);
            bias[v] = x;
        }
        return;
    }

    int g  = l >> 4, c0 = l & 15;
    const float* src;
    int t, kk;
    size_t dst;
    float scale;
    if (fb < 16) {
        t = fb >> 1; kk = fb & 1;
        src = embW;                                   // [64][128]
        dst = (size_t)fb * 1024;
        scale = 1.0f;
    } else {
        int r = fb - 16;                              // (layer*8+t)*12+gate*4+kk
        int layer = r / 96;
        int r2 = r % 96;
        t = r2 / 12;
        int r3 = r2 % 12;
        int gate = r3 >> 2;
        kk = r3 & 3;
        const float* Ws[3] = {Wi, Wo, Wc};
        src = Ws[gate] + (size_t)layer * 128 * 128;   // [128][128]
        dst = 16384 + (size_t)r * 1024;
        scale = (gate == 2) ? TWO_L2E : NEG_L2E;
    }

    bf16x8 v;
#pragma unroll
    for (int e = 0; e < 8; ++e) {
        int k   = kk * 32 + g * 8 + e;
        int col = t * 16 + c0;
        v[e] = (short)f2bf(scale * src[(size_t)k * 128 + col]);
    }
    *reinterpret_cast<bf16x8*>(ws + dst + (size_t)l * 16) = v;
}

// ---------------------------------------------------------------------------
// One step of the 16-step chain (layer = STEP>>3, T = STEP&7), 64 rows/wave:
//   bias-splat acc init -> 48 MFMAs from BUF -> WAR-reload BUF for STEP+1 ->
//   16-element activation (single-rcp rational).
// ---------------------------------------------------------------------------
template<int STEP>
__device__ __forceinline__ void t_step(
        bf16x8 (&BUF)[12],
        const bf16x8 (&A)[4][4],
        const char* __restrict__ frags,
        const float* __restrict__ biasf,
        float (&msum)[8],
        unsigned short (* __restrict__ hb)[136],
        int l, int g, int c0) {

    constexpr int L = STEP >> 3;
    constexpr int T = STEP & 7;
    const int c = T * 16 + c0;
    const float Bi = biasf[L * 384 + c];
    const float Bo = biasf[L * 384 + 128 + c];
    const float Bc = biasf[L * 384 + 256 + c];

    f32x4 ai[4], ao[4], ac[4];
#pragma unroll
    for (int mi = 0; mi < 4; ++mi) {
        ai[mi] = f32x4{Bi, Bi, Bi, Bi};     // bias folded into C-input
        ao[mi] = f32x4{Bo, Bo, Bo, Bo};
        ac[mi] = f32x4{Bc, Bc, Bc, Bc};
    }
#pragma unroll
    for (int kk = 0; kk < 4; ++kk) {
#pragma unroll
        for (int mi = 0; mi < 4; ++mi) {
            ai[mi] = MFMA16(A[mi][kk], BUF[kk],     ai[mi]);
            ao[mi] = MFMA16(A[mi][kk], BUF[4 + kk], ao[mi]);
            ac[mi] = MFMA16(A[mi][kk], BUF[8 + kk], ac[mi]);
        }
    }

    // WAR reload: loads issue after the MFMAs consumed BUF; L2 latency hides
    // under the activation block below.
    if constexpr (STEP < 15) {
        const char* src = frags + 16384 + (size_t)(STEP + 1) * 12288 + (size_t)l * 16;
#pragma unroll
        for (int i = 0; i < 12; ++i)
            BUF[i] = *reinterpret_cast<const bf16x8*>(src + (size_t)i * 1024);
    }

#pragma unroll
    for (int mi = 0; mi < 4; ++mi) {
#pragma unroll
        for (int r = 0; r < 4; ++r) {
            // logits pre-scaled: ai = -log2e*i, ao = -log2e*o, ac = 2log2e*c
            float ei = fexp2(ai[mi][r]);              // e^-i
            float eo = fexp2(ao[mi][r]);              // e^-o
            float u  = fexp2(ac[mi][r]);              // e^{2c}
            float p  = u - 1.0f;
            float q  = (1.0f + ei) * (u + 1.0f);      // cc = p/q = sig(i)tanh(c~)
            float p2 = p * p,  q2 = q * q;
            float p4 = p2 * p2, q4 = q2 * q2, pq = p2 * q2;
            float N  = p4 + 105.0f * pq + 945.0f * q4;          // Pade[5/4] num
            float D  = 15.0f * p4 + 420.0f * pq + 945.0f * q4;  // Pade[5/4] den
            float h  = p * N * frcp(q * D * (1.0f + eo));       // one rcp total
            if constexpr (L == 1) {
                msum[T] += h;
            } else {
                hb[mi * 16 + g * 4 + r][c] = f2bf(h);
            }
        }
    }
}

// ---------------------------------------------------------------------------
// Main fused kernel: 512 blocks x 256 threads; each wave owns 64 rows.
// No block-wide barriers until the final reduce.
// ---------------------------------------------------------------------------
__global__ __launch_bounds__(256) void tree_enc(
        const float* __restrict__ X,       // [131072][64]
        const float* __restrict__ emb_b,   // [128]
        const char*  __restrict__ frags,   // ws
        float* __restrict__ out) {         // [256][128]

    __shared__ __align__(16) unsigned short hbuf[4][64][136];   // 69632 B
    __shared__ float redbuf[4][128];                            //  2048 B

    const int tid = threadIdx.x;
    const int w   = tid >> 6;
    const int l   = tid & 63;
    const int g   = l >> 4;
    const int c0  = l & 15;
    const int rowbase = blockIdx.x * 256 + w * 64;
    const int b  = blockIdx.x >> 1;       // 2 blocks per batch

    unsigned short (* __restrict__ hb)[136] = hbuf[w];
    const float* biasf = reinterpret_cast<const float*>(frags + 212992);

    // ---------------- embedding: h0 = X @ embW + emb_b ----------------
    {
        bf16x8 afr[4][2];
#pragma unroll
        for (int mi = 0; mi < 4; ++mi) {
#pragma unroll
            for (int kk = 0; kk < 2; ++kk) {
                int row = rowbase + mi * 16 + c0;
                const float4* p = reinterpret_cast<const float4*>(
                        X + (size_t)row * 64 + kk * 32 + g * 8);
                float4 v0 = p[0], v1 = p[1];
                bf16x8 a;
                a[0] = (short)f2bf(v0.x); a[1] = (short)f2bf(v0.y);
                a[2] = (short)f2bf(v0.z); a[3] = (short)f2bf(v0.w);
                a[4] = (short)f2bf(v1.x); a[5] = (short)f2bf(v1.y);
                a[6] = (short)f2bf(v1.z); a[7] = (short)f2bf(v1.w);
                afr[mi][kk] = a;
            }
        }
#pragma unroll
        for (int t = 0; t < 8; ++t) {
            const float be = emb_b[t * 16 + c0];
            f32x4 acc[4];
#pragma unroll
            for (int mi = 0; mi < 4; ++mi) acc[mi] = f32x4{be, be, be, be};
#pragma unroll
            for (int kk = 0; kk < 2; ++kk) {
                bf16x8 bf = *reinterpret_cast<const bf16x8*>(
                        frags + ((size_t)(t * 2 + kk) * 64 + l) * 16);
#pragma unroll
                for (int mi = 0; mi < 4; ++mi)
                    acc[mi] = MFMA16(afr[mi][kk], bf, acc[mi]);
            }
#pragma unroll
            for (int mi = 0; mi < 4; ++mi)
#pragma unroll
                for (int r = 0; r < 4; ++r)
                    hb[mi * 16 + g * 4 + r][t * 16 + c0] =
                        f2bf(acc[mi][r]);   // C: col=l&15, row=4*(l>>4)+r
        }
    }

    // ---------------- 2 TreeLSTM layers (no barriers) ----------------
    float msum[8];
#pragma unroll
    for (int t = 0; t < 8; ++t) msum[t] = 0.f;

    bf16x8 A[4][4];
    bf16x8 BUF[12];

    // A-frags of h0; initial fragment buffer for step 0
#pragma unroll
    for (int mi = 0; mi < 4; ++mi)
#pragma unroll
        for (int kk = 0; kk < 4; ++kk)
            A[mi][kk] = *reinterpret_cast<const bf16x8*>(
                    &hb[mi * 16 + c0][kk * 32 + g * 8]);
    {
        const char* s0 = frags + 16384 + (size_t)l * 16;
#pragma unroll
        for (int i = 0; i < 12; ++i)
            BUF[i] = *reinterpret_cast<const bf16x8*>(s0 + (size_t)i * 1024);
    }

    t_step< 0>(BUF, A, frags, biasf, msum, hb, l, g, c0);
    t_step< 1>(BUF, A, frags, biasf, msum, hb, l, g, c0);
    t_step< 2>(BUF, A, frags, biasf, msum, hb, l, g, c0);
    t_step< 3>(BUF, A, frags, biasf, msum, hb, l, g, c0);
    t_step< 4>(BUF, A, frags, biasf, msum, hb, l, g, c0);
    t_step< 5>(BUF, A, frags, biasf, msum, hb, l, g, c0);
    t_step< 6>(BUF, A, frags, biasf, msum, hb, l, g, c0);
    t_step< 7>(BUF, A, frags, biasf, msum, hb, l, g, c0);

    // layer switch: hbuf now holds h1 (wave-private, DS in-order per wave)
#pragma unroll
    for (int mi = 0; mi < 4; ++mi)
#pragma unroll
        for (int kk = 0; kk < 4; ++kk)
            A[mi][kk] = *reinterpret_cast<const bf16x8*>(
                    &hb[mi * 16 + c0][kk * 32 + g * 8]);

    t_step< 8>(BUF, A, frags, biasf, msum, hb, l, g, c0);
    t_step< 9>(BUF, A, frags, biasf, msum, hb, l, g, c0);
    t_step<10>(BUF, A, frags, biasf, msum, hb, l, g, c0);
    t_step<11>(BUF, A, frags, biasf, msum, hb, l, g, c0);
    t_step<12>(BUF, A, frags, biasf, msum, hb, l, g, c0);
    t_step<13>(BUF, A, frags, biasf, msum, hb, l, g, c0);
    t_step<14>(BUF, A, frags, biasf, msum, hb, l, g, c0);
    t_step<15>(BUF, A, frags, biasf, msum, hb, l, g, c0);

    // ---------------- mean over nodes (single barrier) ----------------
#pragma unroll
    for (int t = 0; t < 8; ++t) {
        float v = msum[t];
        v += __shfl_xor(v, 16);
        v += __shfl_xor(v, 32);
        if (g == 0) redbuf[w][t * 16 + c0] = v;
    }
    __syncthreads();
    if (tid < 128) {
        float s = redbuf[0][tid] + redbuf[1][tid] + redbuf[2][tid] + redbuf[3][tid];
        atomicAdd(&out[b * 128 + tid], s * (1.0f / 512.0f));
    }
}

// ---------------------------------------------------------------------------
extern "C" void kernel_launch(void* const* d_in, const int* in_sizes, int n_in,
                              void* d_out, int out_size, void* d_ws, size_t ws_size,
                              hipStream_t stream) {
    const float* X    = (const float*)d_in[0];
    const float* embW = (const float*)d_in[1];
    const float* embb = (const float*)d_in[2];
    const float* Wi   = (const float*)d_in[3];
    const float* Wo   = (const float*)d_in[4];
    const float* Wc   = (const float*)d_in[5];
    const float* bWi  = (const float*)d_in[6];
    const float* bUi  = (const float*)d_in[7];
    const float* bWo  = (const float*)d_in[8];
    const float* bUo  = (const float*)d_in[9];
    const float* bWc  = (const float*)d_in[10];
    const float* bUc  = (const float*)d_in[11];
    float* out = (float*)d_out;
    char*  ws  = (char*)d_ws;

    hipMemsetAsync(d_out, 0, (size_t)out_size * sizeof(float), stream);
    prep_frags<<<209, 64, 0, stream>>>(embW, Wi, Wo, Wc,
                                       bWi, bUi, bWo, bUo, bWc, bUc, ws);
    tree_enc<<<512, 256, 0, stream>>>(X, embb, (const char*)ws, out);
}

// Round 11
// 65.110 us; speedup vs baseline: 1.2336x; 1.2336x over previous
//
#include <hip/hip_runtime.h>

// ---------------------------------------------------------------------------
// TreeEncoder fused MFMA kernel, round 11.
//   r7(3w/SIMD)=83.5, r8(4w)=59.4, r10(2w)=76 -> resident-wave count is the
//   dominant term; r8's config (32 rows/wave, VGPR=128, zero barriers) is the
//   best measured point. r11 keeps that skeleton and cuts the largest busy
//   pipe (VALU ~28us):
//   - Pade[3/2] tanh, homogeneous: h = p(15q^2+p^2)/(q(15q^2+6p^2)(1+eo))
//     14 VALU + 3 exp2 + 1 rcp per element (was ~22 VALU + 5 trans).
//     |cc| <~ 0.5 on this data -> approx error < 5e-6.
//   - packed-f32 pairs (float2 ext_vector) so the backend can emit
//     v_pk_fma/mul/add_f32 (VOP3P) for the rational part.
//   - bias-splat accumulator init (from r10): bias rides the MFMA C-input.
// ---------------------------------------------------------------------------

typedef short bf16x8 __attribute__((ext_vector_type(8)));
typedef float f32x4  __attribute__((ext_vector_type(4)));
typedef float f32x2  __attribute__((ext_vector_type(2)));

#define MFMA16(a, b, c) __builtin_amdgcn_mfma_f32_16x16x32_bf16((a), (b), (c), 0, 0, 0)

#define NEG_L2E (-1.44269504088896f)
#define TWO_L2E (2.88539008177793f)

__device__ __forceinline__ unsigned short f2bf(float f) {
    return (unsigned short)((__float_as_uint(f) + 0x8000u) >> 16);
}
__device__ __forceinline__ float frcp(float x)  { return __builtin_amdgcn_rcpf(x); }
__device__ __forceinline__ float fexp2(float x) { return __builtin_amdgcn_exp2f(x); }

// ---------------------------------------------------------------------------
// Prep: weights -> MFMA B-fragment bf16 layout in ws, with exp2 prescale;
// plus combined scaled biases.  (identical to rounds 8/9/10)
//   ws map (bytes):
//     [0, 16384)        emb_W: block = t*2 + kk          (unscaled)
//     [16384, 212992)   gates: block = (layer*8+t)*12 + gate*4 + kk
//         gate 0/1 (Wi,Wo): * -log2e    gate 2 (Wc): * 2*log2e
//     [212992, 216064)  biases: float[2][3][128], same scaling, bW+bU combined
// ---------------------------------------------------------------------------
__global__ void prep_frags(const float* __restrict__ embW,
                           const float* __restrict__ Wi,
                           const float* __restrict__ Wo,
                           const float* __restrict__ Wc,
                           const float* __restrict__ bWi, const float* __restrict__ bUi,
                           const float* __restrict__ bWo, const float* __restrict__ bUo,
                           const float* __restrict__ bWc, const float* __restrict__ bUc,
                           char* __restrict__ ws) {
    int fb = blockIdx.x;          // 0..208
    int l  = threadIdx.x;         // 0..63

    if (fb == 208) {              // combined scaled biases: [layer][gate][128]
        float* bias = reinterpret_cast<float*>(ws + 212992);
#pragma unroll
        for (int j = 0; j < 12; ++j) {
            int v = j * 64 + l;                 // 0..767
            int layer = v / 384;
            int r = v % 384;
            int gate = r >> 7;
            int c = r & 127;
            int idx = layer * 128 + c;
            float x;
            if (gate == 0)      x = NEG_L2E * (bWi[idx] + bUi[idx]);
            else if (gate == 1) x = NEG_L2E * (bWo[idx] + bUo[idx]);
            else                x = TWO_L2E * (bWc[idx] + bUc[idx]);
            bias[v] = x;
        }
        return;
    }

    int g  = l >> 4, c0 = l & 15;
    const float* src;
    int t, kk;
    size_t dst;
    float scale;
    if (fb < 16) {
        t = fb >> 1; kk = fb & 1;
        src = embW;                                   // [64][128]
        dst = (size_t)fb * 1024;
        scale = 1.0f;
    } else {
        int r = fb - 16;                              // (layer*8+t)*12+gate*4+kk
        int layer = r / 96;
        int r2 = r % 96;
        t = r2 / 12;
        int r3 = r2 % 12;
        int gate = r3 >> 2;
        kk = r3 & 3;
        const float* Ws[3] = {Wi, Wo, Wc};
        src = Ws[gate] + (size_t)layer * 128 * 128;   // [128][128]
        dst = 16384 + (size_t)r * 1024;
        scale = (gate == 2) ? TWO_L2E : NEG_L2E;
    }

    bf16x8 v;
#pragma unroll
    for (int e = 0; e < 8; ++e) {
        int k   = kk * 32 + g * 8 + e;
        int col = t * 16 + c0;
        v[e] = (short)f2bf(scale * src[(size_t)k * 128 + col]);
    }
    *reinterpret_cast<bf16x8*>(ws + dst + (size_t)l * 16) = v;
}

// ---------------------------------------------------------------------------
// One step (layer = STEP>>3, T = STEP&7), 32 rows/wave:
//   bias-splat acc init -> 24 MFMAs from BUF -> WAR-reload BUF (STEP+1) ->
//   packed Pade[3/2] activation.
// ---------------------------------------------------------------------------
template<int STEP>
__device__ __forceinline__ void t_step(
        bf16x8 (&BUF)[12],
        const bf16x8 (&A)[2][4],
        const char* __restrict__ frags,
        const float* __restrict__ biasf,
        float (&msum)[8],
        unsigned short (* __restrict__ hb)[136],
        int l, int g, int c0) {

    constexpr int L = STEP >> 3;
    constexpr int T = STEP & 7;
    const int c = T * 16 + c0;
    const float Bi = biasf[L * 384 + c];
    const float Bo = biasf[L * 384 + 128 + c];
    const float Bc = biasf[L * 384 + 256 + c];

    f32x4 ai[2], ao[2], ac[2];
#pragma unroll
    for (int mi = 0; mi < 2; ++mi) {
        ai[mi] = f32x4{Bi, Bi, Bi, Bi};     // bias rides the MFMA C-input
        ao[mi] = f32x4{Bo, Bo, Bo, Bo};
        ac[mi] = f32x4{Bc, Bc, Bc, Bc};
    }
#pragma unroll
    for (int kk = 0; kk < 4; ++kk) {
#pragma unroll
        for (int mi = 0; mi < 2; ++mi) {
            ac[mi] = MFMA16(A[mi][kk], BUF[8 + kk], ac[mi]);   // c first: its exp
            ai[mi] = MFMA16(A[mi][kk], BUF[kk],     ai[mi]);   // is first consumer
            ao[mi] = MFMA16(A[mi][kk], BUF[4 + kk], ao[mi]);
        }
    }

    // WAR reload: loads issue after the MFMAs consumed BUF; L2 latency hides
    // under the activation block below.
    if constexpr (STEP < 15) {
        const char* src = frags + 16384 + (size_t)(STEP + 1) * 12288 + (size_t)l * 16;
#pragma unroll
        for (int i = 0; i < 12; ++i)
            BUF[i] = *reinterpret_cast<const bf16x8*>(src + (size_t)i * 1024);
    }

    // packed Pade[3/2] activation:
    //   p = u-1, q = (1+ei)(u+1);  cc = p/q = sigmoid(i)*tanh(c~)
    //   h = p(15q^2+p^2) / (q(15q^2+6p^2)(1+eo))
#pragma unroll
    for (int mi = 0; mi < 2; ++mi) {
#pragma unroll
        for (int j = 0; j < 2; ++j) {
            f32x2 ei2 = { fexp2(ai[mi][2 * j]), fexp2(ai[mi][2 * j + 1]) };
            f32x2 eo2 = { fexp2(ao[mi][2 * j]), fexp2(ao[mi][2 * j + 1]) };
            f32x2 uu  = { fexp2(ac[mi][2 * j]), fexp2(ac[mi][2 * j + 1]) };
            f32x2 p   = uu - 1.0f;
            f32x2 q   = (1.0f + ei2) * (uu + 1.0f);
            f32x2 p2  = p * p;
            f32x2 q2  = q * q;
            f32x2 t15 = 15.0f * q2;
            f32x2 pn  = p * (t15 + p2);
            f32x2 qd  = q * (6.0f * p2 + t15);
            f32x2 den = qd * (1.0f + eo2);
            f32x2 hh  = pn * f32x2{ frcp(den.x), frcp(den.y) };
            if constexpr (L == 1) {
                msum[T] += hh.x + hh.y;
            } else {
                hb[mi * 16 + g * 4 + 2 * j][c]     = f2bf(hh.x);
                hb[mi * 16 + g * 4 + 2 * j + 1][c] = f2bf(hh.y);
            }
        }
    }
}

// ---------------------------------------------------------------------------
// Main fused kernel: 1024 blocks x 256 threads; each wave owns 32 rows.
// Zero inner barriers; VGPR pinned to 128 (4 waves/SIMD, r8-proven).
// ---------------------------------------------------------------------------
__global__ __launch_bounds__(256)
__attribute__((amdgpu_num_vgpr(128)))
void tree_enc(
        const float* __restrict__ X,       // [131072][64]
        const float* __restrict__ emb_b,   // [128]
        const char*  __restrict__ frags,   // ws
        float* __restrict__ out) {         // [256][128]

    __shared__ __align__(16) unsigned short hbuf[4][32][136];   // 34816 B
    __shared__ float redbuf[4][128];                            //  2048 B

    const int tid = threadIdx.x;
    const int w   = tid >> 6;
    const int l   = tid & 63;
    const int g   = l >> 4;
    const int c0  = l & 15;
    const int rowbase = blockIdx.x * 128 + w * 32;
    const int b  = blockIdx.x >> 2;       // 4 blocks per batch

    unsigned short (* __restrict__ hb)[136] = hbuf[w];
    const float* biasf = reinterpret_cast<const float*>(frags + 212992);

    // ---------------- embedding: h0 = X @ embW + emb_b ----------------
    {
        bf16x8 afr[2][2];
#pragma unroll
        for (int mi = 0; mi < 2; ++mi) {
#pragma unroll
            for (int kk = 0; kk < 2; ++kk) {
                int row = rowbase + mi * 16 + c0;
                const float4* p = reinterpret_cast<const float4*>(
                        X + (size_t)row * 64 + kk * 32 + g * 8);
                float4 v0 = p[0], v1 = p[1];
                bf16x8 a;
                a[0] = (short)f2bf(v0.x); a[1] = (short)f2bf(v0.y);
                a[2] = (short)f2bf(v0.z); a[3] = (short)f2bf(v0.w);
                a[4] = (short)f2bf(v1.x); a[5] = (short)f2bf(v1.y);
                a[6] = (short)f2bf(v1.z); a[7] = (short)f2bf(v1.w);
                afr[mi][kk] = a;
            }
        }
#pragma unroll
        for (int t = 0; t < 8; ++t) {
            const float be = emb_b[t * 16 + c0];
            f32x4 acc[2] = { f32x4{be, be, be, be}, f32x4{be, be, be, be} };
#pragma unroll
            for (int kk = 0; kk < 2; ++kk) {
                bf16x8 bf = *reinterpret_cast<const bf16x8*>(
                        frags + ((size_t)(t * 2 + kk) * 64 + l) * 16);
#pragma unroll
                for (int mi = 0; mi < 2; ++mi)
                    acc[mi] = MFMA16(afr[mi][kk], bf, acc[mi]);
            }
#pragma unroll
            for (int mi = 0; mi < 2; ++mi)
#pragma unroll
                for (int r = 0; r < 4; ++r)
                    hb[mi * 16 + g * 4 + r][t * 16 + c0] =
                        f2bf(acc[mi][r]);   // C: col=l&15, row=4*(l>>4)+r
        }
    }

    // ---------------- 2 TreeLSTM layers (no barriers) ----------------
    float msum[8];
#pragma unroll
    for (int t = 0; t < 8; ++t) msum[t] = 0.f;

    bf16x8 A[2][4];
    bf16x8 BUF[12];

    // A-frags of h0; initial fragment buffer for step 0
#pragma unroll
    for (int mi = 0; mi < 2; ++mi)
#pragma unroll
        for (int kk = 0; kk < 4; ++kk)
            A[mi][kk] = *reinterpret_cast<const bf16x8*>(
                    &hb[mi * 16 + c0][kk * 32 + g * 8]);
    {
        const char* s0 = frags + 16384 + (size_t)l * 16;
#pragma unroll
        for (int i = 0; i < 12; ++i)
            BUF[i] = *reinterpret_cast<const bf16x8*>(s0 + (size_t)i * 1024);
    }

    t_step< 0>(BUF, A, frags, biasf, msum, hb, l, g, c0);
    t_step< 1>(BUF, A, frags, biasf, msum, hb, l, g, c0);
    t_step< 2>(BUF, A, frags, biasf, msum, hb, l, g, c0);
    t_step< 3>(BUF, A, frags, biasf, msum, hb, l, g, c0);
    t_step< 4>(BUF, A, frags, biasf, msum, hb, l, g, c0);
    t_step< 5>(BUF, A, frags, biasf, msum, hb, l, g, c0);
    t_step< 6>(BUF, A, frags, biasf, msum, hb, l, g, c0);
    t_step< 7>(BUF, A, frags, biasf, msum, hb, l, g, c0);

    // layer switch: hbuf now holds h1 (wave-private, DS in-order per wave)
#pragma unroll
    for (int mi = 0; mi < 2; ++mi)
#pragma unroll
        for (int kk = 0; kk < 4; ++kk)
            A[mi][kk] = *reinterpret_cast<const bf16x8*>(
                    &hb[mi * 16 + c0][kk * 32 + g * 8]);

    t_step< 8>(BUF, A, frags, biasf, msum, hb, l, g, c0);
    t_step< 9>(BUF, A, frags, biasf, msum, hb, l, g, c0);
    t_step<10>(BUF, A, frags, biasf, msum, hb, l, g, c0);
    t_step<11>(BUF, A, frags, biasf, msum, hb, l, g, c0);
    t_step<12>(BUF, A, frags, biasf, msum, hb, l, g, c0);
    t_step<13>(BUF, A, frags, biasf, msum, hb, l, g, c0);
    t_step<14>(BUF, A, frags, biasf, msum, hb, l, g, c0);
    t_step<15>(BUF, A, frags, biasf, msum, hb, l, g, c0);

    // ---------------- mean over nodes (single barrier) ----------------
#pragma unroll
    for (int t = 0; t < 8; ++t) {
        float v = msum[t];
        v += __shfl_xor(v, 16);
        v += __shfl_xor(v, 32);
        if (g == 0) redbuf[w][t * 16 + c0] = v;
    }
    __syncthreads();
    if (tid < 128) {
        float s = redbuf[0][tid] + redbuf[1][tid] + redbuf[2][tid] + redbuf[3][tid];
        atomicAdd(&out[b * 128 + tid], s * (1.0f / 512.0f));
    }
}

// ---------------------------------------------------------------------------
extern "C" void kernel_launch(void* const* d_in, const int* in_sizes, int n_in,
                              void* d_out, int out_size, void* d_ws, size_t ws_size,
                              hipStream_t stream) {
    const float* X    = (const float*)d_in[0];
    const float* embW = (const float*)d_in[1];
    const float* embb = (const float*)d_in[2];
    const float* Wi   = (const float*)d_in[3];
    const float* Wo   = (const float*)d_in[4];
    const float* Wc   = (const float*)d_in[5];
    const float* bWi  = (const float*)d_in[6];
    const float* bUi  = (const float*)d_in[7];
    const float* bWo  = (const float*)d_in[8];
    const float* bUo  = (const float*)d_in[9];
    const float* bWc  = (const float*)d_in[10];
    const float* bUc  = (const float*)d_in[11];
    float* out = (float*)d_out;
    char*  ws  = (char*)d_ws;

    hipMemsetAsync(d_out, 0, (size_t)out_size * sizeof(float), stream);
    prep_frags<<<209, 64, 0, stream>>>(embW, Wi, Wo, Wc,
                                       bWi, bUi, bWo, bUo, bWc, bUc, ws);
    tree_enc<<<1024, 256, 0, stream>>>(X, embb, (const char*)ws, out);
}